// Round 3
// baseline (1523.868 us; speedup 1.0000x reference)
//
#include <hip/hip_runtime.h>

#define NB    16
#define CIN   64
#define TT    512
#define VV    22
#define COUT  256
#define TBK   4            // t per z tile
#define NTB   (TT / TBK)   // 128
#define ZROW  (TBK * VV)   // 88
#define XT    68           // xs_t / Yt row stride (floats)
#define SP    25           // Ss / Ps row stride (25 coprime 32 -> conflict-free)
#define ZS    92           // k2 Zs row stride
#define PAD   24           // fallback kernel pads
#define OPAD  23

// ===================== Kernel 0: prep  M=Wa^T Wb, g=Wa^T bb, h=Wb^T ba, s0=ba.bb =====================
// scr layout (in d_out head, overwritten later by k2): [0,4096) M[c][c'], [4096,4160) g, [4160,4224) h, [4224] s0
__global__ void agcn_prep(const float* __restrict__ Wa, const float* __restrict__ Wb,
                          const float* __restrict__ ba, const float* __restrict__ bb,
                          float* __restrict__ scr)
{
    const int tid = threadIdx.x;
    for (int o = tid; o < CIN * CIN; o += 256) {
        int c = o >> 6, cp = o & 63;
        float s = 0.f;
        for (int i = 0; i < CIN; ++i) s += Wa[i * CIN + c] * Wb[i * CIN + cp];
        scr[o] = s;
    }
    if (tid < CIN) {
        float s = 0.f;
        for (int i = 0; i < CIN; ++i) s += Wa[i * CIN + tid] * bb[i];
        scr[CIN * CIN + tid] = s;
    } else if (tid < 2 * CIN) {
        int c = tid - CIN;
        float s = 0.f;
        for (int i = 0; i < CIN; ++i) s += ba[i] * Wb[i * CIN + c];
        scr[CIN * CIN + CIN + c] = s;
    } else if (tid == 2 * CIN) {
        float s = 0.f;
        for (int i = 0; i < CIN; ++i) s += ba[i] * bb[i];
        scr[CIN * CIN + 2 * CIN] = s;
    }
}

// ===================== Kernel 1: attention + aggregate =====================
__global__ __launch_bounds__(256, 8) void agcn_attn(
    const float* __restrict__ x, const float* __restrict__ A,
    const float* __restrict__ scr, float* __restrict__ z)
{
    const int bx = blockIdx.x;
    const int t  = (bx & 7) * 64 + (bx >> 3);   // XCD swizzle: t 64-contiguous per XCD
    const int n  = blockIdx.y;
    const int tid = threadIdx.x;

    __shared__ float xs_t[VV * XT];   // [v][c]  X^T
    __shared__ float Yt[VV * XT];     // [v][c]  (MX)^T
    __shared__ float Ss[VV * SP];
    __shared__ float Ps[VV * SP];
    __shared__ float gXs[VV], hXs[VV], s0s[1];

    // P0: stage X^T and A+1e-6
    for (int f = tid; f < CIN * VV; f += 256) {
        int c = f / VV, v = f - c * VV;
        xs_t[v * XT + c] = x[(((size_t)n * CIN + c) * TT + t) * VV + v];
    }
    {
        const float* Ag = A + ((size_t)n * TT + t) * (VV * VV);
        for (int f = tid; f < VV * VV; f += 256) {
            int u = f / VV, v = f - u * VV;
            Ps[u * SP + v] = Ag[f] + 1e-6f;
        }
    }
    __syncthreads();

    // P1: Y = M X. Thread r computes Y[r][u] for its u-quarter; xs_t reads are wave-uniform broadcasts.
    {
        const int r = tid & 63, q = tid >> 6;
        const int us = (q * VV) >> 2, ue = ((q + 1) * VV) >> 2;   // 0/5/11/16 .. 5/11/16/22
        float acc[6] = {0.f, 0.f, 0.f, 0.f, 0.f, 0.f};
        const float* Mr = scr + r * CIN;
        for (int cg = 0; cg < 16; ++cg) {
            float4 m4 = *reinterpret_cast<const float4*>(Mr + cg * 4);
            #pragma unroll
            for (int j = 0; j < 6; ++j) {
                float4 xv = *reinterpret_cast<const float4*>(&xs_t[(us + j) * XT + cg * 4]);
                acc[j] += m4.x * xv.x + m4.y * xv.y + m4.z * xv.z + m4.w * xv.w;
            }
        }
        #pragma unroll
        for (int j = 0; j < 6; ++j)
            if (us + j < ue) Yt[(us + j) * XT + r] = acc[j];   // lanes r consecutive: conflict-free
    }
    // bias-term vectors (zero in this problem, kept for generality; cheap)
    if (tid < VV) {
        const float* g = scr + CIN * CIN;
        float s = 0.f;
        for (int cg = 0; cg < 16; ++cg) {
            float4 g4 = *reinterpret_cast<const float4*>(g + cg * 4);
            float4 xv = *reinterpret_cast<const float4*>(&xs_t[tid * XT + cg * 4]);
            s += g4.x * xv.x + g4.y * xv.y + g4.z * xv.z + g4.w * xv.w;
        }
        gXs[tid] = s;
    } else if (tid < 2 * VV) {
        const int v = tid - VV;
        const float* h = scr + CIN * CIN + CIN;
        float s = 0.f;
        for (int cg = 0; cg < 16; ++cg) {
            float4 h4 = *reinterpret_cast<const float4*>(h + cg * 4);
            float4 xv = *reinterpret_cast<const float4*>(&xs_t[v * XT + cg * 4]);
            s += h4.x * xv.x + h4.y * xv.y + h4.z * xv.z + h4.w * xv.w;
        }
        hXs[v] = s;
    } else if (tid == 2 * VV) {
        s0s[0] = scr[CIN * CIN + 2 * CIN];
    }
    __syncthreads();

    // P2: S[u][v] = (x_u . y_v + gX[u] + hX[v] + s0) / 64
    for (int idx = tid; idx < VV * VV; idx += 256) {
        int u = idx / VV, v = idx - u * VV;
        float s = 0.f;
        for (int cg = 0; cg < 16; ++cg) {
            float4 xv = *reinterpret_cast<const float4*>(&xs_t[u * XT + cg * 4]);
            float4 yv = *reinterpret_cast<const float4*>(&Yt[v * XT + cg * 4]);
            s += xv.x * yv.x + xv.y * yv.y + xv.z * yv.z + xv.w * yv.w;
        }
        Ss[u * SP + v] = (s + gXs[u] + hXs[v] + s0s[0]) * (1.0f / 64.0f);
    }
    __syncthreads();

    // P3: softmax over u per column v; Ps += softmax
    if (tid < VV) {
        const int v = tid;
        float m = -1e30f;
        #pragma unroll
        for (int u = 0; u < VV; ++u) m = fmaxf(m, Ss[u * SP + v]);
        float sum = 0.f;
        #pragma unroll
        for (int u = 0; u < VV; ++u) sum += __expf(Ss[u * SP + v] - m);
        const float inv = 1.0f / sum;
        #pragma unroll
        for (int u = 0; u < VV; ++u)
            Ps[u * SP + v] += __expf(Ss[u * SP + v] - m) * inv;
    }
    __syncthreads();

    // P4: z[c][u] = sum_w Ps[u][w] * X[c][w]; thread = (u, c-quad). 352 work items.
    {
        const int tb = t >> 2, ttl = t & 3;
        float* zd = z + (((size_t)n * NTB + tb) * CIN) * ZROW + ttl * VV;
        #pragma unroll
        for (int rep = 0; rep < 2; ++rep) {
            int idx = rep * 256 + tid;
            if (idx < 16 * VV) {
                int u = idx % VV, c4 = idx / VV;
                float ax = 0.f, ay = 0.f, az = 0.f, aw = 0.f;
                #pragma unroll
                for (int w = 0; w < VV; ++w) {
                    float p = Ps[u * SP + w];                       // lanes: distinct u, stride 25 -> conflict-free
                    float4 xv = *reinterpret_cast<const float4*>(&xs_t[w * XT + c4 * 4]);  // ~broadcast
                    ax += p * xv.x; ay += p * xv.y; az += p * xv.z; aw += p * xv.w;
                }
                zd[(size_t)(c4 * 4 + 0) * ZROW + u] = ax;
                zd[(size_t)(c4 * 4 + 1) * ZROW + u] = ay;
                zd[(size_t)(c4 * 4 + 2) * ZROW + u] = az;
                zd[(size_t)(c4 * 4 + 3) * ZROW + u] = aw;
            }
        }
    }
}

// ===================== Kernel 2: out = relu(Wd @ z + bd) =====================
// Block (tb, ob, n): M=64 o, N=88 tv, K=64. Thread (ty,tx): 4 o x 6 tv.
__global__ __launch_bounds__(256, 6) void agcn_out(
    const float* __restrict__ z, const float* __restrict__ Wd,
    const float* __restrict__ bd, float* __restrict__ out)
{
    const int bxx = blockIdx.x;                  // 0..127
    const int tb  = (bxx & 7) * 16 + (bxx >> 3); // XCD swizzle aligned with k1
    const int ob  = blockIdx.y;                  // 0..3
    const int n   = blockIdx.z;
    const int tid = threadIdx.x;
    const int tx = tid & 15, ty = tid >> 4;
    const int o0 = ob * 64 + ty * 4;
    const int col0 = tx * 6;

    __shared__ float Zs[CIN * ZS + 8];   // [k][col], stride 92; +8 pad for tail reads

    {
        const float* zsrc = z + (((size_t)n * NTB + tb) * CIN) * ZROW;
        for (int i4 = tid; i4 < (CIN * ZROW) / 4; i4 += 256) {
            float4 val = *reinterpret_cast<const float4*>(zsrc + (size_t)i4 * 4);
            int c = i4 / (ZROW / 4), r4 = (i4 % (ZROW / 4)) * 4;
            *reinterpret_cast<float4*>(&Zs[c * ZS + r4]) = val;
        }
    }
    __syncthreads();

    float acc[4][6];
    #pragma unroll
    for (int j = 0; j < 4; ++j) {
        const float b = bd[o0 + j];
        #pragma unroll
        for (int m = 0; m < 6; ++m) acc[j][m] = b;
    }

    for (int kg = 0; kg < 16; ++kg) {
        const int k = kg * 4;
        float4 w0 = *reinterpret_cast<const float4*>(&Wd[(size_t)(o0 + 0) * CIN + k]);
        float4 w1 = *reinterpret_cast<const float4*>(&Wd[(size_t)(o0 + 1) * CIN + k]);
        float4 w2 = *reinterpret_cast<const float4*>(&Wd[(size_t)(o0 + 2) * CIN + k]);
        float4 w3 = *reinterpret_cast<const float4*>(&Wd[(size_t)(o0 + 3) * CIN + k]);
        const float wv0[4] = {w0.x, w0.y, w0.z, w0.w};
        const float wv1[4] = {w1.x, w1.y, w1.z, w1.w};
        const float wv2[4] = {w2.x, w2.y, w2.z, w2.w};
        const float wv3[4] = {w3.x, w3.y, w3.z, w3.w};
        #pragma unroll
        for (int kk = 0; kk < 4; ++kk) {
            const float* zr = &Zs[(k + kk) * ZS + col0];
            float2 za = *reinterpret_cast<const float2*>(zr);
            float2 zb = *reinterpret_cast<const float2*>(zr + 2);
            float2 zc = *reinterpret_cast<const float2*>(zr + 4);
            const float zv[6] = {za.x, za.y, zb.x, zb.y, zc.x, zc.y};
            #pragma unroll
            for (int m = 0; m < 6; ++m) {
                acc[0][m] += wv0[kk] * zv[m];
                acc[1][m] += wv1[kk] * zv[m];
                acc[2][m] += wv2[kk] * zv[m];
                acc[3][m] += wv3[kk] * zv[m];
            }
        }
    }

    // store: float2 pairs, masked at col >= 88
    #pragma unroll
    for (int j = 0; j < 4; ++j) {
        float* op = out + ((size_t)(n * COUT + o0 + j)) * (TT * VV) + (size_t)tb * ZROW + col0;
        #pragma unroll
        for (int m = 0; m < 6; m += 2) {
            if (col0 + m < ZROW) {
                float2 sv = {fmaxf(acc[j][m], 0.f), fmaxf(acc[j][m + 1], 0.f)};
                *reinterpret_cast<float2*>(op + m) = sv;
            }
        }
    }
}

// ===================== Fallback: verified R1 monolithic kernel =====================
__global__ __launch_bounds__(256, 4) void agcn_fused(
    const float* __restrict__ x, const float* __restrict__ A,
    const float* __restrict__ Wa, const float* __restrict__ ba,
    const float* __restrict__ Wb, const float* __restrict__ bb,
    const float* __restrict__ Wd, const float* __restrict__ bd,
    float* __restrict__ out)
{
    const int t   = blockIdx.x;
    const int n   = blockIdx.y;
    const int tid = threadIdx.x;
    __shared__ float smem[7424];
    float* xs   = smem;
    float* A1s  = smem + 1536;
    float* A2s  = smem + 3072;
    float* Ssf  = smem + 4608;
    float* Psf  = smem + 5136;
    float* outs = smem;
    float* zs   = smem + 5888;

    for (int f = tid; f < CIN * VV; f += 256) {
        int c = f / VV, v = f - c * VV;
        xs[c * PAD + v] = x[(((size_t)n * CIN + c) * TT + t) * VV + v];
    }
    {
        const float* Ag = A + (((size_t)n * TT + t) * VV) * VV;
        for (int f = tid; f < VV * VV; f += 256) {
            int u = f / VV, v = f - u * VV;
            Psf[u * PAD + v] = Ag[f] + 1e-6f;
        }
    }
    __syncthreads();
    {
        const int r  = tid & 63;
        const int q  = tid >> 6;
        const int us = (q * VV) >> 2;
        const int ue = ((q + 1) * VV) >> 2;
        const float* War = Wa + r * CIN;
        const float* Wbr = Wb + r * CIN;
        float acc1[6], acc2[6];
        const float b1 = ba[r], b2 = bb[r];
        #pragma unroll
        for (int u = 0; u < 6; ++u) { acc1[u] = b1; acc2[u] = b2; }
        for (int c = 0; c < CIN; c += 4) {
            float4 wa4 = *reinterpret_cast<const float4*>(War + c);
            float4 wb4 = *reinterpret_cast<const float4*>(Wbr + c);
            #pragma unroll
            for (int u = 0; u < 6; ++u) {
                float x0 = xs[(c + 0) * PAD + us + u];
                float x1 = xs[(c + 1) * PAD + us + u];
                float x2 = xs[(c + 2) * PAD + us + u];
                float x3 = xs[(c + 3) * PAD + us + u];
                acc1[u] += wa4.x * x0 + wa4.y * x1 + wa4.z * x2 + wa4.w * x3;
                acc2[u] += wb4.x * x0 + wb4.y * x1 + wb4.z * x2 + wb4.w * x3;
            }
        }
        #pragma unroll
        for (int u = 0; u < 6; ++u) {
            if (us + u < ue) {
                A1s[r * PAD + us + u] = acc1[u];
                A2s[r * PAD + us + u] = acc2[u];
            }
        }
    }
    __syncthreads();
    for (int f = tid; f < VV * VV; f += 256) {
        int u = f / VV, v = f - u * VV;
        float s = 0.f;
        for (int i = 0; i < CIN; ++i)
            s += A1s[i * PAD + u] * A2s[i * PAD + v];
        Ssf[u * PAD + v] = s * (1.0f / 64.0f);
    }
    __syncthreads();
    if (tid < VV) {
        const int v = tid;
        float m = -1e30f;
        #pragma unroll
        for (int u = 0; u < VV; ++u) m = fmaxf(m, Ssf[u * PAD + v]);
        float sum = 0.f;
        #pragma unroll
        for (int u = 0; u < VV; ++u) sum += __expf(Ssf[u * PAD + v] - m);
        const float inv = 1.0f / sum;
        #pragma unroll
        for (int u = 0; u < VV; ++u)
            Psf[u * PAD + v] += __expf(Ssf[u * PAD + v] - m) * inv;
    }
    __syncthreads();
    for (int f = tid; f < CIN * VV; f += 256) {
        int c = f / VV, u = f - c * VV;
        float s = 0.f;
        #pragma unroll
        for (int w = 0; w < VV; ++w)
            s += Psf[u * PAD + w] * xs[c * PAD + w];
        zs[c * PAD + u] = s;
    }
    __syncthreads();
    {
        const int o = tid;
        const float* Wr = Wd + o * CIN;
        float acc[VV];
        const float b = bd[o];
        #pragma unroll
        for (int u = 0; u < VV; ++u) acc[u] = b;
        for (int c = 0; c < CIN; c += 4) {
            float4 w4 = *reinterpret_cast<const float4*>(Wr + c);
            #pragma unroll
            for (int cc = 0; cc < 4; ++cc) {
                const float w = (cc == 0) ? w4.x : (cc == 1) ? w4.y : (cc == 2) ? w4.z : w4.w;
                const float* zr = zs + (c + cc) * PAD;
                #pragma unroll
                for (int uq = 0; uq < 5; ++uq) {
                    float4 zq = *reinterpret_cast<const float4*>(zr + uq * 4);
                    acc[uq * 4 + 0] += w * zq.x;
                    acc[uq * 4 + 1] += w * zq.y;
                    acc[uq * 4 + 2] += w * zq.z;
                    acc[uq * 4 + 3] += w * zq.w;
                }
                float2 zt = *reinterpret_cast<const float2*>(zr + 20);
                acc[20] += w * zt.x;
                acc[21] += w * zt.y;
            }
        }
        #pragma unroll
        for (int u = 0; u < VV; ++u)
            outs[o * OPAD + u] = fmaxf(acc[u], 0.f);
    }
    __syncthreads();
    {
        const size_t obase = (size_t)n * COUT * TT * VV + (size_t)t * VV;
        for (int f = tid; f < COUT * VV; f += 256) {
            int o = f / VV, u = f - o * VV;
            out[obase + (size_t)o * (TT * VV) + u] = outs[o * OPAD + u];
        }
    }
}

extern "C" void kernel_launch(void* const* d_in, const int* in_sizes, int n_in,
                              void* d_out, int out_size, void* d_ws, size_t ws_size,
                              hipStream_t stream) {
    const float* x  = (const float*)d_in[0];
    const float* A  = (const float*)d_in[1];
    const float* Wa = (const float*)d_in[2];
    const float* ba = (const float*)d_in[3];
    const float* Wb = (const float*)d_in[4];
    const float* bb = (const float*)d_in[5];
    const float* Wd = (const float*)d_in[6];
    const float* bd = (const float*)d_in[7];
    float* outp     = (float*)d_out;

    const size_t z_bytes = (size_t)NB * TT * CIN * VV * sizeof(float);  // 46.1 MB
    if (ws_size >= z_bytes) {
        float* zws = (float*)d_ws;
        // scr lives in the head of d_out; k2 overwrites all of d_out afterwards (stream-ordered).
        agcn_prep<<<1, 256, 0, stream>>>(Wa, Wb, ba, bb, outp);
        dim3 g1(TT, NB);
        agcn_attn<<<g1, 256, 0, stream>>>(x, A, outp, zws);
        dim3 g2(NTB, COUT / 64, NB);
        agcn_out<<<g2, 256, 0, stream>>>(zws, Wd, bd, outp);
    } else {
        dim3 grid(TT, NB);
        agcn_fused<<<grid, 256, 0, stream>>>(x, A, Wa, ba, Wb, bb, Wd, bd, outp);
    }
}

// Round 4
// 1144.620 us; speedup vs baseline: 1.3313x; 1.3313x over previous
//
#include <hip/hip_runtime.h>

#define NB    16
#define CIN   64
#define TT    512
#define VV    22
#define COUT  256
#define TBK   4            // t per z tile
#define NTB   (TT / TBK)   // 128
#define ZROW  (TBK * VV)   // 88
#define XT    68           // xs_t / Yt row stride (floats)
#define SP    25           // Ss / Ps row stride (25 coprime 32 -> conflict-free)
#define ZS    92           // k2 Zs row stride
#define PAD   24           // fallback kernel pads
#define OPAD  23

// ===================== Kernel 0: prep  M=Wa^T Wb, g=Wa^T bb, h=Wb^T ba, s0=ba.bb =====================
// scr layout (in d_out head, overwritten later by k2): [0,4096) M[c][c'], [4096,4160) g, [4160,4224) h, [4224] s0
__global__ void agcn_prep(const float* __restrict__ Wa, const float* __restrict__ Wb,
                          const float* __restrict__ ba, const float* __restrict__ bb,
                          float* __restrict__ scr)
{
    const int tid = threadIdx.x;
    for (int o = tid; o < CIN * CIN; o += 256) {
        int c = o >> 6, cp = o & 63;
        float s = 0.f;
        for (int i = 0; i < CIN; ++i) s += Wa[i * CIN + c] * Wb[i * CIN + cp];
        scr[o] = s;
    }
    if (tid < CIN) {
        float s = 0.f;
        for (int i = 0; i < CIN; ++i) s += Wa[i * CIN + tid] * bb[i];
        scr[CIN * CIN + tid] = s;
    } else if (tid < 2 * CIN) {
        int c = tid - CIN;
        float s = 0.f;
        for (int i = 0; i < CIN; ++i) s += ba[i] * Wb[i * CIN + c];
        scr[CIN * CIN + CIN + c] = s;
    } else if (tid == 2 * CIN) {
        float s = 0.f;
        for (int i = 0; i < CIN; ++i) s += ba[i] * bb[i];
        scr[CIN * CIN + 2 * CIN] = s;
    }
}

// ===================== Kernel 1: attention + aggregate =====================
// launch_bounds(256,4): ~128 VGPR budget -> NO SPILLS (R3's (256,8) forced 32 VGPRs
// and spilled GBs of scratch traffic). 4 blocks/CU via 67KB LDS is enough TLP.
__global__ __launch_bounds__(256, 4) void agcn_attn(
    const float* __restrict__ x, const float* __restrict__ A,
    const float* __restrict__ scr, float* __restrict__ z)
{
    const int bx = blockIdx.x;
    const int t  = (bx & 7) * 64 + (bx >> 3);   // XCD swizzle: t 64-contiguous per XCD
    const int n  = blockIdx.y;
    const int tid = threadIdx.x;

    __shared__ float xs_t[VV * XT];   // [v][c]  X^T
    __shared__ float Yt[VV * XT];     // [v][c]  (MX)^T
    __shared__ float Ss[VV * SP];
    __shared__ float Ps[VV * SP];
    __shared__ float gXs[VV], hXs[VV], s0s[1];

    // P0: stage X^T and A+1e-6
    for (int f = tid; f < CIN * VV; f += 256) {
        int c = f / VV, v = f - c * VV;
        xs_t[v * XT + c] = x[(((size_t)n * CIN + c) * TT + t) * VV + v];
    }
    {
        const float* Ag = A + ((size_t)n * TT + t) * (VV * VV);
        for (int f = tid; f < VV * VV; f += 256) {
            int u = f / VV, v = f - u * VV;
            Ps[u * SP + v] = Ag[f] + 1e-6f;
        }
    }
    __syncthreads();

    // P1: Y = M X. Thread r computes Y[r][u] for its u-quarter; xs_t reads are wave-uniform broadcasts.
    {
        const int r = tid & 63, q = tid >> 6;
        const int us = (q * VV) >> 2, ue = ((q + 1) * VV) >> 2;   // 0/5/11/16 .. 5/11/16/22
        float acc[6] = {0.f, 0.f, 0.f, 0.f, 0.f, 0.f};
        const float* Mr = scr + r * CIN;
        for (int cg = 0; cg < 16; ++cg) {
            float4 m4 = *reinterpret_cast<const float4*>(Mr + cg * 4);
            #pragma unroll
            for (int j = 0; j < 6; ++j) {
                float4 xv = *reinterpret_cast<const float4*>(&xs_t[(us + j) * XT + cg * 4]);
                acc[j] += m4.x * xv.x + m4.y * xv.y + m4.z * xv.z + m4.w * xv.w;
            }
        }
        #pragma unroll
        for (int j = 0; j < 6; ++j)
            if (us + j < ue) Yt[(us + j) * XT + r] = acc[j];   // lanes r consecutive: conflict-free
    }
    // bias-term vectors (zero in this problem, kept for generality; cheap)
    if (tid < VV) {
        const float* g = scr + CIN * CIN;
        float s = 0.f;
        for (int cg = 0; cg < 16; ++cg) {
            float4 g4 = *reinterpret_cast<const float4*>(g + cg * 4);
            float4 xv = *reinterpret_cast<const float4*>(&xs_t[tid * XT + cg * 4]);
            s += g4.x * xv.x + g4.y * xv.y + g4.z * xv.z + g4.w * xv.w;
        }
        gXs[tid] = s;
    } else if (tid < 2 * VV) {
        const int v = tid - VV;
        const float* h = scr + CIN * CIN + CIN;
        float s = 0.f;
        for (int cg = 0; cg < 16; ++cg) {
            float4 h4 = *reinterpret_cast<const float4*>(h + cg * 4);
            float4 xv = *reinterpret_cast<const float4*>(&xs_t[v * XT + cg * 4]);
            s += h4.x * xv.x + h4.y * xv.y + h4.z * xv.z + h4.w * xv.w;
        }
        hXs[v] = s;
    } else if (tid == 2 * VV) {
        s0s[0] = scr[CIN * CIN + 2 * CIN];
    }
    __syncthreads();

    // P2: S[u][v] = (x_u . y_v + gX[u] + hX[v] + s0) / 64
    for (int idx = tid; idx < VV * VV; idx += 256) {
        int u = idx / VV, v = idx - u * VV;
        float s = 0.f;
        for (int cg = 0; cg < 16; ++cg) {
            float4 xv = *reinterpret_cast<const float4*>(&xs_t[u * XT + cg * 4]);
            float4 yv = *reinterpret_cast<const float4*>(&Yt[v * XT + cg * 4]);
            s += xv.x * yv.x + xv.y * yv.y + xv.z * yv.z + xv.w * yv.w;
        }
        Ss[u * SP + v] = (s + gXs[u] + hXs[v] + s0s[0]) * (1.0f / 64.0f);
    }
    __syncthreads();

    // P3: softmax over u per column v; Ps += softmax
    if (tid < VV) {
        const int v = tid;
        float m = -1e30f;
        #pragma unroll
        for (int u = 0; u < VV; ++u) m = fmaxf(m, Ss[u * SP + v]);
        float sum = 0.f;
        #pragma unroll
        for (int u = 0; u < VV; ++u) sum += __expf(Ss[u * SP + v] - m);
        const float inv = 1.0f / sum;
        #pragma unroll
        for (int u = 0; u < VV; ++u)
            Ps[u * SP + v] += __expf(Ss[u * SP + v] - m) * inv;
    }
    __syncthreads();

    // P4: z[c][u] = sum_w Ps[u][w] * X[c][w]; thread = (u, c-quad). 352 work items.
    {
        const int tb = t >> 2, ttl = t & 3;
        float* zd = z + (((size_t)n * NTB + tb) * CIN) * ZROW + ttl * VV;
        #pragma unroll
        for (int rep = 0; rep < 2; ++rep) {
            int idx = rep * 256 + tid;
            if (idx < 16 * VV) {
                int u = idx % VV, c4 = idx / VV;
                float ax = 0.f, ay = 0.f, az = 0.f, aw = 0.f;
                #pragma unroll
                for (int w = 0; w < VV; ++w) {
                    float p = Ps[u * SP + w];                       // lanes: distinct u, stride 25 -> conflict-free
                    float4 xv = *reinterpret_cast<const float4*>(&xs_t[w * XT + c4 * 4]);  // ~broadcast
                    ax += p * xv.x; ay += p * xv.y; az += p * xv.z; aw += p * xv.w;
                }
                zd[(size_t)(c4 * 4 + 0) * ZROW + u] = ax;
                zd[(size_t)(c4 * 4 + 1) * ZROW + u] = ay;
                zd[(size_t)(c4 * 4 + 2) * ZROW + u] = az;
                zd[(size_t)(c4 * 4 + 3) * ZROW + u] = aw;
            }
        }
    }
}

// ===================== Kernel 2: out = relu(Wd @ z + bd) =====================
// Block (tb, ob, n): M=64 o, N=88 tv, K=64. Thread (ty,tx): 4 o x 6 tv.
// launch_bounds(256,4): ~128 VGPR budget (no spill); occupancy LDS-limited anyway.
__global__ __launch_bounds__(256, 4) void agcn_out(
    const float* __restrict__ z, const float* __restrict__ Wd,
    const float* __restrict__ bd, float* __restrict__ out)
{
    const int bxx = blockIdx.x;                  // 0..127
    const int tb  = (bxx & 7) * 16 + (bxx >> 3); // XCD swizzle aligned with k1
    const int ob  = blockIdx.y;                  // 0..3
    const int n   = blockIdx.z;
    const int tid = threadIdx.x;
    const int tx = tid & 15, ty = tid >> 4;
    const int o0 = ob * 64 + ty * 4;
    const int col0 = tx * 6;

    __shared__ float Zs[CIN * ZS + 8];   // [k][col], stride 92; +8 pad for tail reads

    {
        const float* zsrc = z + (((size_t)n * NTB + tb) * CIN) * ZROW;
        for (int i4 = tid; i4 < (CIN * ZROW) / 4; i4 += 256) {
            float4 val = *reinterpret_cast<const float4*>(zsrc + (size_t)i4 * 4);
            int c = i4 / (ZROW / 4), r4 = (i4 % (ZROW / 4)) * 4;
            *reinterpret_cast<float4*>(&Zs[c * ZS + r4]) = val;
        }
    }
    __syncthreads();

    float acc[4][6];
    #pragma unroll
    for (int j = 0; j < 4; ++j) {
        const float b = bd[o0 + j];
        #pragma unroll
        for (int m = 0; m < 6; ++m) acc[j][m] = b;
    }

    for (int kg = 0; kg < 16; ++kg) {
        const int k = kg * 4;
        float4 w0 = *reinterpret_cast<const float4*>(&Wd[(size_t)(o0 + 0) * CIN + k]);
        float4 w1 = *reinterpret_cast<const float4*>(&Wd[(size_t)(o0 + 1) * CIN + k]);
        float4 w2 = *reinterpret_cast<const float4*>(&Wd[(size_t)(o0 + 2) * CIN + k]);
        float4 w3 = *reinterpret_cast<const float4*>(&Wd[(size_t)(o0 + 3) * CIN + k]);
        const float wv0[4] = {w0.x, w0.y, w0.z, w0.w};
        const float wv1[4] = {w1.x, w1.y, w1.z, w1.w};
        const float wv2[4] = {w2.x, w2.y, w2.z, w2.w};
        const float wv3[4] = {w3.x, w3.y, w3.z, w3.w};
        #pragma unroll
        for (int kk = 0; kk < 4; ++kk) {
            const float* zr = &Zs[(k + kk) * ZS + col0];
            float2 za = *reinterpret_cast<const float2*>(zr);
            float2 zb = *reinterpret_cast<const float2*>(zr + 2);
            float2 zc = *reinterpret_cast<const float2*>(zr + 4);
            const float zv[6] = {za.x, za.y, zb.x, zb.y, zc.x, zc.y};
            #pragma unroll
            for (int m = 0; m < 6; ++m) {
                acc[0][m] += wv0[kk] * zv[m];
                acc[1][m] += wv1[kk] * zv[m];
                acc[2][m] += wv2[kk] * zv[m];
                acc[3][m] += wv3[kk] * zv[m];
            }
        }
    }

    // store: float2 pairs, masked at col >= 88
    #pragma unroll
    for (int j = 0; j < 4; ++j) {
        float* op = out + ((size_t)(n * COUT + o0 + j)) * (TT * VV) + (size_t)tb * ZROW + col0;
        #pragma unroll
        for (int m = 0; m < 6; m += 2) {
            if (col0 + m < ZROW) {
                float2 sv = {fmaxf(acc[j][m], 0.f), fmaxf(acc[j][m + 1], 0.f)};
                *reinterpret_cast<float2*>(op + m) = sv;
            }
        }
    }
}

// ===================== Fallback: verified R1 monolithic kernel =====================
__global__ __launch_bounds__(256, 4) void agcn_fused(
    const float* __restrict__ x, const float* __restrict__ A,
    const float* __restrict__ Wa, const float* __restrict__ ba,
    const float* __restrict__ Wb, const float* __restrict__ bb,
    const float* __restrict__ Wd, const float* __restrict__ bd,
    float* __restrict__ out)
{
    const int t   = blockIdx.x;
    const int n   = blockIdx.y;
    const int tid = threadIdx.x;
    __shared__ float smem[7424];
    float* xs   = smem;
    float* A1s  = smem + 1536;
    float* A2s  = smem + 3072;
    float* Ssf  = smem + 4608;
    float* Psf  = smem + 5136;
    float* outs = smem;
    float* zs   = smem + 5888;

    for (int f = tid; f < CIN * VV; f += 256) {
        int c = f / VV, v = f - c * VV;
        xs[c * PAD + v] = x[(((size_t)n * CIN + c) * TT + t) * VV + v];
    }
    {
        const float* Ag = A + (((size_t)n * TT + t) * VV) * VV;
        for (int f = tid; f < VV * VV; f += 256) {
            int u = f / VV, v = f - u * VV;
            Psf[u * PAD + v] = Ag[f] + 1e-6f;
        }
    }
    __syncthreads();
    {
        const int r  = tid & 63;
        const int q  = tid >> 6;
        const int us = (q * VV) >> 2;
        const int ue = ((q + 1) * VV) >> 2;
        const float* War = Wa + r * CIN;
        const float* Wbr = Wb + r * CIN;
        float acc1[6], acc2[6];
        const float b1 = ba[r], b2 = bb[r];
        #pragma unroll
        for (int u = 0; u < 6; ++u) { acc1[u] = b1; acc2[u] = b2; }
        for (int c = 0; c < CIN; c += 4) {
            float4 wa4 = *reinterpret_cast<const float4*>(War + c);
            float4 wb4 = *reinterpret_cast<const float4*>(Wbr + c);
            #pragma unroll
            for (int u = 0; u < 6; ++u) {
                float x0 = xs[(c + 0) * PAD + us + u];
                float x1 = xs[(c + 1) * PAD + us + u];
                float x2 = xs[(c + 2) * PAD + us + u];
                float x3 = xs[(c + 3) * PAD + us + u];
                acc1[u] += wa4.x * x0 + wa4.y * x1 + wa4.z * x2 + wa4.w * x3;
                acc2[u] += wb4.x * x0 + wb4.y * x1 + wb4.z * x2 + wb4.w * x3;
            }
        }
        #pragma unroll
        for (int u = 0; u < 6; ++u) {
            if (us + u < ue) {
                A1s[r * PAD + us + u] = acc1[u];
                A2s[r * PAD + us + u] = acc2[u];
            }
        }
    }
    __syncthreads();
    for (int f = tid; f < VV * VV; f += 256) {
        int u = f / VV, v = f - u * VV;
        float s = 0.f;
        for (int i = 0; i < CIN; ++i)
            s += A1s[i * PAD + u] * A2s[i * PAD + v];
        Ssf[u * PAD + v] = s * (1.0f / 64.0f);
    }
    __syncthreads();
    if (tid < VV) {
        const int v = tid;
        float m = -1e30f;
        #pragma unroll
        for (int u = 0; u < VV; ++u) m = fmaxf(m, Ssf[u * PAD + v]);
        float sum = 0.f;
        #pragma unroll
        for (int u = 0; u < VV; ++u) sum += __expf(Ssf[u * PAD + v] - m);
        const float inv = 1.0f / sum;
        #pragma unroll
        for (int u = 0; u < VV; ++u)
            Psf[u * PAD + v] += __expf(Ssf[u * PAD + v] - m) * inv;
    }
    __syncthreads();
    for (int f = tid; f < CIN * VV; f += 256) {
        int c = f / VV, u = f - c * VV;
        float s = 0.f;
        #pragma unroll
        for (int w = 0; w < VV; ++w)
            s += Psf[u * PAD + w] * xs[c * PAD + w];
        zs[c * PAD + u] = s;
    }
    __syncthreads();
    {
        const int o = tid;
        const float* Wr = Wd + o * CIN;
        float acc[VV];
        const float b = bd[o];
        #pragma unroll
        for (int u = 0; u < VV; ++u) acc[u] = b;
        for (int c = 0; c < CIN; c += 4) {
            float4 w4 = *reinterpret_cast<const float4*>(Wr + c);
            #pragma unroll
            for (int cc = 0; cc < 4; ++cc) {
                const float w = (cc == 0) ? w4.x : (cc == 1) ? w4.y : (cc == 2) ? w4.z : w4.w;
                const float* zr = zs + (c + cc) * PAD;
                #pragma unroll
                for (int uq = 0; uq < 5; ++uq) {
                    float4 zq = *reinterpret_cast<const float4*>(zr + uq * 4);
                    acc[uq * 4 + 0] += w * zq.x;
                    acc[uq * 4 + 1] += w * zq.y;
                    acc[uq * 4 + 2] += w * zq.z;
                    acc[uq * 4 + 3] += w * zq.w;
                }
                float2 zt = *reinterpret_cast<const float2*>(zr + 20);
                acc[20] += w * zt.x;
                acc[21] += w * zt.y;
            }
        }
        #pragma unroll
        for (int u = 0; u < VV; ++u)
            outs[o * OPAD + u] = fmaxf(acc[u], 0.f);
    }
    __syncthreads();
    {
        const size_t obase = (size_t)n * COUT * TT * VV + (size_t)t * VV;
        for (int f = tid; f < COUT * VV; f += 256) {
            int o = f / VV, u = f - o * VV;
            out[obase + (size_t)o * (TT * VV) + u] = outs[o * OPAD + u];
        }
    }
}

extern "C" void kernel_launch(void* const* d_in, const int* in_sizes, int n_in,
                              void* d_out, int out_size, void* d_ws, size_t ws_size,
                              hipStream_t stream) {
    const float* x  = (const float*)d_in[0];
    const float* A  = (const float*)d_in[1];
    const float* Wa = (const float*)d_in[2];
    const float* ba = (const float*)d_in[3];
    const float* Wb = (const float*)d_in[4];
    const float* bb = (const float*)d_in[5];
    const float* Wd = (const float*)d_in[6];
    const float* bd = (const float*)d_in[7];
    float* outp     = (float*)d_out;

    const size_t z_bytes = (size_t)NB * TT * CIN * VV * sizeof(float);  // 46.1 MB
    if (ws_size >= z_bytes) {
        float* zws = (float*)d_ws;
        // scr lives in the head of d_out; k2 overwrites all of d_out afterwards (stream-ordered).
        agcn_prep<<<1, 256, 0, stream>>>(Wa, Wb, ba, bb, outp);
        dim3 g1(TT, NB);
        agcn_attn<<<g1, 256, 0, stream>>>(x, A, outp, zws);
        dim3 g2(NTB, COUT / 64, NB);
        agcn_out<<<g2, 256, 0, stream>>>(zws, Wd, bd, outp);
    } else {
        dim3 grid(TT, NB);
        agcn_fused<<<grid, 256, 0, stream>>>(x, A, Wa, ba, Wb, bb, Wd, bd, outp);
    }
}

// Round 5
// 277.598 us; speedup vs baseline: 5.4895x; 4.1233x over previous
//
#include <hip/hip_runtime.h>

#define NB    16
#define CIN   64
#define TT    512
#define VV    22
#define COUT  256
#define TBK   4            // t per z tile
#define NTB   (TT / TBK)   // 128
#define ZROW  (TBK * VV)   // 88
#define ZS    92           // k2 Zs row stride
#define PAD   24           // LDS row stride for 22-wide tiles
#define OPAD  23

// ===================== Kernel 1: attention + aggregate (R2-proven structure) =====================
// Direct A1/A2 computation; one block per (n,t); z stored in (N, T/TBK, C, TBK, V) layout.
__global__ __launch_bounds__(256, 6) void agcn_attn(
    const float* __restrict__ x, const float* __restrict__ A,
    const float* __restrict__ Wa, const float* __restrict__ ba,
    const float* __restrict__ Wb, const float* __restrict__ bb,
    float* __restrict__ z)
{
    const int bx = blockIdx.x;
    const int t  = (bx & 7) * 64 + (bx >> 3);   // XCD swizzle: t 64-contiguous per XCD
    const int n  = blockIdx.y;
    const int tid = threadIdx.x;

    __shared__ float xs[CIN * PAD];
    __shared__ float A1s[CIN * PAD];
    __shared__ float A2s[CIN * PAD];
    __shared__ float Ss[VV * PAD];
    __shared__ float Ps[VV * PAD];

    // ---- Phase 0: stage x[n,:,t,:] (64x22) and A tile (22x22) ----
    for (int f = tid; f < CIN * VV; f += 256) {
        int c = f / VV, v = f - c * VV;
        xs[c * PAD + v] = x[(((size_t)n * CIN + c) * TT + t) * VV + v];
    }
    {
        const float* Ag = A + (((size_t)n * TT + t) * VV) * VV;
        for (int f = tid; f < VV * VV; f += 256) {
            int u = f / VV, v = f - u * VV;
            Ps[u * PAD + v] = Ag[f] + 1e-6f;
        }
    }
    __syncthreads();

    // ---- Phase 1: A1 = Wa@xs + ba, A2 = Wb@xs + bb ----
    {
        const int r  = tid & 63;
        const int q  = tid >> 6;
        const int us = (q * VV) >> 2;
        const int ue = ((q + 1) * VV) >> 2;
        const float* War = Wa + r * CIN;
        const float* Wbr = Wb + r * CIN;
        float acc1[6], acc2[6];
        const float b1 = ba[r], b2 = bb[r];
        #pragma unroll
        for (int u = 0; u < 6; ++u) { acc1[u] = b1; acc2[u] = b2; }
        for (int c = 0; c < CIN; c += 4) {
            float4 wa4 = *reinterpret_cast<const float4*>(War + c);
            float4 wb4 = *reinterpret_cast<const float4*>(Wbr + c);
            #pragma unroll
            for (int u = 0; u < 6; ++u) {
                float x0 = xs[(c + 0) * PAD + us + u];
                float x1 = xs[(c + 1) * PAD + us + u];
                float x2 = xs[(c + 2) * PAD + us + u];
                float x3 = xs[(c + 3) * PAD + us + u];
                acc1[u] += wa4.x * x0 + wa4.y * x1 + wa4.z * x2 + wa4.w * x3;
                acc2[u] += wb4.x * x0 + wb4.y * x1 + wb4.z * x2 + wb4.w * x3;
            }
        }
        #pragma unroll
        for (int u = 0; u < 6; ++u) {
            if (us + u < ue) {
                A1s[r * PAD + us + u] = acc1[u];
                A2s[r * PAD + us + u] = acc2[u];
            }
        }
    }
    __syncthreads();

    // ---- Phase 2: scores ----
    for (int f = tid; f < VV * VV; f += 256) {
        int u = f / VV, v = f - u * VV;
        float s = 0.f;
        #pragma unroll 8
        for (int i = 0; i < CIN; ++i)
            s += A1s[i * PAD + u] * A2s[i * PAD + v];
        Ss[u * PAD + v] = s * (1.0f / 64.0f);
    }
    __syncthreads();

    // ---- Phase 3: softmax over u (per column v); Ps += softmax ----
    if (tid < VV) {
        const int v = tid;
        float m = -1e30f;
        #pragma unroll
        for (int u = 0; u < VV; ++u) m = fmaxf(m, Ss[u * PAD + v]);
        float sum = 0.f;
        #pragma unroll
        for (int u = 0; u < VV; ++u) sum += __expf(Ss[u * PAD + v] - m);
        const float inv = 1.0f / sum;
        #pragma unroll
        for (int u = 0; u < VV; ++u)
            Ps[u * PAD + v] += __expf(Ss[u * PAD + v] - m) * inv;
    }
    __syncthreads();

    // ---- Phase 4: z[c][u] = sum_w Ps[u][w]*xs[c][w], store TBK=4 contiguous layout ----
    {
        const int tb  = t >> 2;
        const int ttl = t & 3;
        float* zdst = z + (((size_t)n * NTB + tb) * CIN) * ZROW + ttl * VV;
        for (int f = tid; f < CIN * VV; f += 256) {
            int c = f / VV, u = f - c * VV;
            float s = 0.f;
            #pragma unroll
            for (int w = 0; w < VV; ++w)
                s += Ps[u * PAD + w] * xs[c * PAD + w];
            zdst[(size_t)c * ZROW + u] = s;
        }
    }
}

// ===================== Kernel 2: out = relu(Wd @ z + bd) (R4-benched) =====================
// Block (tb, ob, n): M=64 o, N=88 tv, K=64. Thread (ty,tx): 4 o x 6 tv. Wd via L1, no LDS stage.
__global__ __launch_bounds__(256, 4) void agcn_out(
    const float* __restrict__ z, const float* __restrict__ Wd,
    const float* __restrict__ bd, float* __restrict__ out)
{
    const int bxx = blockIdx.x;                  // 0..127
    const int tb  = (bxx & 7) * 16 + (bxx >> 3); // XCD swizzle aligned with k1
    const int ob  = blockIdx.y;                  // 0..3
    const int n   = blockIdx.z;
    const int tid = threadIdx.x;
    const int tx = tid & 15, ty = tid >> 4;
    const int o0 = ob * 64 + ty * 4;
    const int col0 = tx * 6;

    __shared__ float Zs[CIN * ZS + 8];   // [k][col], stride 92; +8 pad for tail reads

    {
        const float* zsrc = z + (((size_t)n * NTB + tb) * CIN) * ZROW;
        for (int i4 = tid; i4 < (CIN * ZROW) / 4; i4 += 256) {
            float4 val = *reinterpret_cast<const float4*>(zsrc + (size_t)i4 * 4);
            int c = i4 / (ZROW / 4), r4 = (i4 % (ZROW / 4)) * 4;
            *reinterpret_cast<float4*>(&Zs[c * ZS + r4]) = val;
        }
    }
    __syncthreads();

    float acc[4][6];
    #pragma unroll
    for (int j = 0; j < 4; ++j) {
        const float b = bd[o0 + j];
        #pragma unroll
        for (int m = 0; m < 6; ++m) acc[j][m] = b;
    }

    for (int kg = 0; kg < 16; ++kg) {
        const int k = kg * 4;
        float4 w0 = *reinterpret_cast<const float4*>(&Wd[(size_t)(o0 + 0) * CIN + k]);
        float4 w1 = *reinterpret_cast<const float4*>(&Wd[(size_t)(o0 + 1) * CIN + k]);
        float4 w2 = *reinterpret_cast<const float4*>(&Wd[(size_t)(o0 + 2) * CIN + k]);
        float4 w3 = *reinterpret_cast<const float4*>(&Wd[(size_t)(o0 + 3) * CIN + k]);
        const float wv0[4] = {w0.x, w0.y, w0.z, w0.w};
        const float wv1[4] = {w1.x, w1.y, w1.z, w1.w};
        const float wv2[4] = {w2.x, w2.y, w2.z, w2.w};
        const float wv3[4] = {w3.x, w3.y, w3.z, w3.w};
        #pragma unroll
        for (int kk = 0; kk < 4; ++kk) {
            const float* zr = &Zs[(k + kk) * ZS + col0];
            float2 za = *reinterpret_cast<const float2*>(zr);
            float2 zb = *reinterpret_cast<const float2*>(zr + 2);
            float2 zc = *reinterpret_cast<const float2*>(zr + 4);
            const float zv[6] = {za.x, za.y, zb.x, zb.y, zc.x, zc.y};
            #pragma unroll
            for (int m = 0; m < 6; ++m) {
                acc[0][m] += wv0[kk] * zv[m];
                acc[1][m] += wv1[kk] * zv[m];
                acc[2][m] += wv2[kk] * zv[m];
                acc[3][m] += wv3[kk] * zv[m];
            }
        }
    }

    // store: float2 pairs, masked at col >= 88
    #pragma unroll
    for (int j = 0; j < 4; ++j) {
        float* op = out + ((size_t)(n * COUT + o0 + j)) * (TT * VV) + (size_t)tb * ZROW + col0;
        #pragma unroll
        for (int m = 0; m < 6; m += 2) {
            if (col0 + m < ZROW) {
                float2 sv = {fmaxf(acc[j][m], 0.f), fmaxf(acc[j][m + 1], 0.f)};
                *reinterpret_cast<float2*>(op + m) = sv;
            }
        }
    }
}

// ===================== Fallback: verified R1 monolithic kernel =====================
__global__ __launch_bounds__(256, 4) void agcn_fused(
    const float* __restrict__ x, const float* __restrict__ A,
    const float* __restrict__ Wa, const float* __restrict__ ba,
    const float* __restrict__ Wb, const float* __restrict__ bb,
    const float* __restrict__ Wd, const float* __restrict__ bd,
    float* __restrict__ out)
{
    const int t   = blockIdx.x;
    const int n   = blockIdx.y;
    const int tid = threadIdx.x;
    __shared__ float smem[7424];
    float* xs   = smem;
    float* A1s  = smem + 1536;
    float* A2s  = smem + 3072;
    float* Ssf  = smem + 4608;
    float* Psf  = smem + 5136;
    float* outs = smem;
    float* zs   = smem + 5888;

    for (int f = tid; f < CIN * VV; f += 256) {
        int c = f / VV, v = f - c * VV;
        xs[c * PAD + v] = x[(((size_t)n * CIN + c) * TT + t) * VV + v];
    }
    {
        const float* Ag = A + (((size_t)n * TT + t) * VV) * VV;
        for (int f = tid; f < VV * VV; f += 256) {
            int u = f / VV, v = f - u * VV;
            Psf[u * PAD + v] = Ag[f] + 1e-6f;
        }
    }
    __syncthreads();
    {
        const int r  = tid & 63;
        const int q  = tid >> 6;
        const int us = (q * VV) >> 2;
        const int ue = ((q + 1) * VV) >> 2;
        const float* War = Wa + r * CIN;
        const float* Wbr = Wb + r * CIN;
        float acc1[6], acc2[6];
        const float b1 = ba[r], b2 = bb[r];
        #pragma unroll
        for (int u = 0; u < 6; ++u) { acc1[u] = b1; acc2[u] = b2; }
        for (int c = 0; c < CIN; c += 4) {
            float4 wa4 = *reinterpret_cast<const float4*>(War + c);
            float4 wb4 = *reinterpret_cast<const float4*>(Wbr + c);
            #pragma unroll
            for (int u = 0; u < 6; ++u) {
                float x0 = xs[(c + 0) * PAD + us + u];
                float x1 = xs[(c + 1) * PAD + us + u];
                float x2 = xs[(c + 2) * PAD + us + u];
                float x3 = xs[(c + 3) * PAD + us + u];
                acc1[u] += wa4.x * x0 + wa4.y * x1 + wa4.z * x2 + wa4.w * x3;
                acc2[u] += wb4.x * x0 + wb4.y * x1 + wb4.z * x2 + wb4.w * x3;
            }
        }
        #pragma unroll
        for (int u = 0; u < 6; ++u) {
            if (us + u < ue) {
                A1s[r * PAD + us + u] = acc1[u];
                A2s[r * PAD + us + u] = acc2[u];
            }
        }
    }
    __syncthreads();
    for (int f = tid; f < VV * VV; f += 256) {
        int u = f / VV, v = f - u * VV;
        float s = 0.f;
        for (int i = 0; i < CIN; ++i)
            s += A1s[i * PAD + u] * A2s[i * PAD + v];
        Ssf[u * PAD + v] = s * (1.0f / 64.0f);
    }
    __syncthreads();
    if (tid < VV) {
        const int v = tid;
        float m = -1e30f;
        #pragma unroll
        for (int u = 0; u < VV; ++u) m = fmaxf(m, Ssf[u * PAD + v]);
        float sum = 0.f;
        #pragma unroll
        for (int u = 0; u < VV; ++u) sum += __expf(Ssf[u * PAD + v] - m);
        const float inv = 1.0f / sum;
        #pragma unroll
        for (int u = 0; u < VV; ++u)
            Psf[u * PAD + v] += __expf(Ssf[u * PAD + v] - m) * inv;
    }
    __syncthreads();
    for (int f = tid; f < CIN * VV; f += 256) {
        int c = f / VV, u = f - c * VV;
        float s = 0.f;
        #pragma unroll
        for (int w = 0; w < VV; ++w)
            s += Psf[u * PAD + w] * xs[c * PAD + w];
        zs[c * PAD + u] = s;
    }
    __syncthreads();
    {
        const int o = tid;
        const float* Wr = Wd + o * CIN;
        float acc[VV];
        const float b = bd[o];
        #pragma unroll
        for (int u = 0; u < VV; ++u) acc[u] = b;
        for (int c = 0; c < CIN; c += 4) {
            float4 w4 = *reinterpret_cast<const float4*>(Wr + c);
            #pragma unroll
            for (int cc = 0; cc < 4; ++cc) {
                const float w = (cc == 0) ? w4.x : (cc == 1) ? w4.y : (cc == 2) ? w4.z : w4.w;
                const float* zr = zs + (c + cc) * PAD;
                #pragma unroll
                for (int uq = 0; uq < 5; ++uq) {
                    float4 zq = *reinterpret_cast<const float4*>(zr + uq * 4);
                    acc[uq * 4 + 0] += w * zq.x;
                    acc[uq * 4 + 1] += w * zq.y;
                    acc[uq * 4 + 2] += w * zq.z;
                    acc[uq * 4 + 3] += w * zq.w;
                }
                float2 zt = *reinterpret_cast<const float2*>(zr + 20);
                acc[20] += w * zt.x;
                acc[21] += w * zt.y;
            }
        }
        #pragma unroll
        for (int u = 0; u < VV; ++u)
            outs[o * OPAD + u] = fmaxf(acc[u], 0.f);
    }
    __syncthreads();
    {
        const size_t obase = (size_t)n * COUT * TT * VV + (size_t)t * VV;
        for (int f = tid; f < COUT * VV; f += 256) {
            int o = f / VV, u = f - o * VV;
            out[obase + (size_t)o * (TT * VV) + u] = outs[o * OPAD + u];
        }
    }
}

extern "C" void kernel_launch(void* const* d_in, const int* in_sizes, int n_in,
                              void* d_out, int out_size, void* d_ws, size_t ws_size,
                              hipStream_t stream) {
    const float* x  = (const float*)d_in[0];
    const float* A  = (const float*)d_in[1];
    const float* Wa = (const float*)d_in[2];
    const float* ba = (const float*)d_in[3];
    const float* Wb = (const float*)d_in[4];
    const float* bb = (const float*)d_in[5];
    const float* Wd = (const float*)d_in[6];
    const float* bd = (const float*)d_in[7];
    float* outp     = (float*)d_out;

    const size_t z_bytes = (size_t)NB * TT * CIN * VV * sizeof(float);  // 46.1 MB
    if (ws_size >= z_bytes) {
        float* zws = (float*)d_ws;
        dim3 g1(TT, NB);
        agcn_attn<<<g1, 256, 0, stream>>>(x, A, Wa, ba, Wb, bb, zws);
        dim3 g2(NTB, COUT / 64, NB);
        agcn_out<<<g2, 256, 0, stream>>>(zws, Wd, bd, outp);
    } else {
        dim3 grid(TT, NB);
        agcn_fused<<<grid, 256, 0, stream>>>(x, A, Wa, ba, Wb, bb, Wd, bd, outp);
    }
}